// Round 21
// baseline (2622.817 us; speedup 1.0000x reference)
//
#include <hip/hip_runtime.h>
#include <stdint.h>

// ---------------- workspace layout (4-byte element offsets) ----------------
static constexpr uint32_t OFF_MASK  = 0;        // 66841 floats (dead after prep_weights)
static constexpr uint32_t OFF_HID   = 0;        // 65536 floats (aliases MASK; used by proj1/2)
static constexpr uint32_t OFF_W0XT  = 66844;    // [9][1024]
static constexpr uint32_t OFF_W0H   = 76060;    // [3][9]
static constexpr uint32_t OFF_B0    = 76088;    // [9]
static constexpr uint32_t OFF_W1    = 76100;    // [4][3]
static constexpr uint32_t OFF_B1    = 76112;    // [3]
static constexpr uint32_t OFF_WH2   = 76116;    // 98304 u32 half2; uint4 layout [m][q][w][l]
static constexpr uint32_t OFF_WH1   = 174420;   // [3][256] fp32 h1-weights per column (zero-padded)
static constexpr uint32_t OFF_B2    = 175188;   // [3][252]
static constexpr uint32_t OFF_XPART = 175948;   // [64][1024][9]
static constexpr uint32_t OFF_H2F   = 765772;   // [64][252]

// ---------------- 128-bit helpers ----------------
struct U128 { uint64_t lo, hi; };
__device__ inline U128 mul128(U128 a, U128 b) {
    U128 r; r.lo = a.lo * b.lo;
    r.hi = a.hi * b.lo + a.lo * b.hi + __umul64hi(a.lo, b.lo);
    return r;
}
__device__ inline U128 add128(U128 a, U128 b) {
    U128 r; r.lo = a.lo + b.lo; r.hi = a.hi + b.hi + (r.lo < b.lo); return r;
}
__device__ inline U128 pcg_mult() { U128 m; m.lo = 0x4385df649fccf645ull; m.hi = 0x2360ed051fc65da4ull; return m; }
__device__ inline void pcg_step(U128& st, U128 inc) { st = add128(mul128(st, pcg_mult()), inc); }

// ---------------- numpy PCG64(SeedSequence(0)) — confirmed (round 13) ----------------
__device__ void pcg_init_np(U128& st, U128& inc) {
    const uint32_t IA = 0x43b0d7e5u, MA = 0x931e8875u, IB = 0x8b51f9ddu, MB = 0x58f38dedu;
    const uint32_t ML = 0xca01f9ddu, MR = 0x4973f715u;
    uint32_t hc = IA;
    auto hmix = [&](uint32_t val) -> uint32_t {
        val ^= hc; hc *= MA; val *= hc; val ^= val >> 16; return val;
    };
    auto mixf = [&](uint32_t x, uint32_t y) -> uint32_t {
        uint32_t r = (x * ML) - (y * MR); r ^= r >> 16; return r;   // SUB mix (round-13 fix)
    };
    uint32_t pool[4];
    for (int i = 0; i < 4; i++) pool[i] = hmix(0u);
    for (int s = 0; s < 4; s++)
        for (int d = 0; d < 4; d++)
            if (s != d) pool[d] = mixf(pool[d], hmix(pool[s]));
    uint32_t hb = IB;
    uint32_t s32[8];
    for (int i = 0; i < 8; i++) {
        uint32_t dv = pool[i & 3];
        dv ^= hb; hb *= MB; dv *= hb; dv ^= dv >> 16;
        s32[i] = dv;
    }
    uint64_t w[4];
    for (int k = 0; k < 4; k++)
        w[k] = (uint64_t)s32[2 * k] | ((uint64_t)s32[2 * k + 1] << 32);
    U128 initstate; initstate.hi = w[0]; initstate.lo = w[1];
    inc.lo = (w[3] << 1) | 1ull;
    inc.hi = (w[2] << 1) | (w[3] >> 63);
    st.lo = 0; st.hi = 0;
    pcg_step(st, inc);
    st = add128(st, initstate);
    pcg_step(st, inc);
}
__device__ inline uint64_t pcg_draw(U128& st, U128 inc) {
    pcg_step(st, inc);
    uint64_t x = st.hi ^ st.lo;
    uint32_t rot = (uint32_t)(st.hi >> 58);
    return (x >> rot) | (x << ((64u - rot) & 63u));
}
__device__ void pcg_advance(U128& st, U128 inc, uint64_t delta) {
    U128 am; am.lo = 1; am.hi = 0;
    U128 ap; ap.lo = 0; ap.hi = 0;
    U128 cm = pcg_mult(), cp = inc;
    while (delta) {
        if (delta & 1) { am = mul128(am, cm); ap = add128(mul128(ap, cm), cp); }
        U128 cm1 = cm; cm1.lo += 1; cm1.hi += (cm1.lo == 0);
        cp = mul128(cm1, cp);
        cm = mul128(cm, cm);
        delta >>= 1;
    }
    st = add128(mul128(st, am), ap);
}

// ---------------- mask generation ----------------
__global__ __launch_bounds__(256) void gen_masks(float* __restrict__ mask) {
    const int tid = threadIdx.x;
    U128 s, inc; pcg_init_np(s, inc);
    pcg_advance(s, inc, (uint64_t)tid * 262u);
    uint32_t base = (uint32_t)tid * 262u;
    for (uint32_t q = 0; q < 262u; q++) {
        uint64_t o = pcg_draw(s, inc);
        uint32_t idx = base + q;
        if (idx < 66841u) mask[idx] = (o >> 63) ? 0.0f : 1.0f;
    }
}

// ---------------- weight preprocessing ----------------
// WH2 uint4 layout [m][q][w][l]: lin = ((m*16+q)*8 + w)*64 + l; component cc holds
// half2 pair p = (l>>5)*64 + q*4 + cc -> l2 rows (1+2p, 2+2p), column jp = w*32 + (l&31).
__global__ __launch_bounds__(256) void prep_weights(
    const float* f1w0, const float* f2w0, const float* taw0, const float* tbw0,
    const float* f1b0, const float* f2b0, const float* tab0, const float* tbb0,
    const float* f1w1, const float* f2w1, const float* taw1, const float* tbw1,
    const float* f1b1, const float* f2b1, const float* tab1, const float* tbb1,
    const float* f1w2, const float* f2w2, const float* taw2, const float* tbw2,
    const float* f1b2, const float* f2b2, const float* tab2, const float* tbb2,
    float* ws)
{
    const float* mask = ws + OFF_MASK;
    uint32_t id = blockIdx.x * 256u + threadIdx.x;
    if (id < 98304u) {
        uint32_t lin = id >> 2, cc = id & 3u;
        uint32_t m = lin / 8192u, rem = lin % 8192u;
        uint32_t q = rem / 512u, r2 = rem % 512u;
        uint32_t w = r2 / 64u, l = r2 % 64u;
        uint32_t kh = l >> 5, c = l & 31u;
        uint32_t p = kh * 64u + q * 4u + cc;
        uint32_t jp = w * 32u + c;
        auto wv = [&](uint32_t k) -> float {
            if (m == 0u) return f1w2[k * 252u + jp] * mask[3085u + k * 252u + jp];
            if (m == 1u) return f2w2[k * 252u + jp] * mask[3085u + k * 252u + jp];
            return taw2[k * 252u + jp] + tbw2[k * 252u + jp];
        };
        float a = 0.0f, bb = 0.0f;
        if (jp < 252u && p < 126u) { a = wv(1u + 2u * p); bb = wv(2u + 2u * p); }
        union { uint32_t u; _Float16 h[2]; } pk;
        pk.h[0] = (_Float16)a; pk.h[1] = (_Float16)bb;
        ((uint32_t*)ws)[OFF_WH2 + lin * 4u + cc] = pk.u;
        return;
    }
    uint32_t t = id - 98304u;
    if (t < 768u) {  // WH1 fp32 (l2 row 0 = h1 weight), zero-padded to 256
        uint32_t mm = t / 256u, jp = t % 256u;
        float v = 0.0f;
        if (jp < 252u) {
            if (mm == 0u)      v = f1w2[jp] * mask[3085u + jp];
            else if (mm == 1u) v = f2w2[jp] * mask[3085u + jp];
            else               v = taw2[jp] + tbw2[jp];
        }
        ws[OFF_WH1 + t] = v;
        return;
    }
    t -= 768u;
    if (t < 9216u) {  // W0xT [c][k]
        uint32_t c = t / 1024u, k = t % 1024u, m = c / 3u, cc = c % 3u;
        float v;
        if (m == 0u)      v = f1w0[k * 3u + cc] * mask[k * 3u + cc];
        else if (m == 1u) v = f2w0[k * 3u + cc] * mask[k * 3u + cc];
        else              v = taw0[k * 3u + cc] + tbw0[k * 3u + cc];
        ws[OFF_W0XT + c * 1024u + k] = v;
        return;
    }
    t -= 9216u;
    if (t < 27u) {  // W0h [i][c]
        uint32_t i = t / 9u, c = t % 9u, m = c / 3u, cc = c % 3u, k = 1024u + i;
        float v;
        if (m == 0u)      v = f1w0[k * 3u + cc] * mask[k * 3u + cc];
        else if (m == 1u) v = f2w0[k * 3u + cc] * mask[k * 3u + cc];
        else              v = taw0[k * 3u + cc] + tbw0[k * 3u + cc];
        ws[OFF_W0H + t] = v;
        return;
    }
    t -= 27u;
    if (t < 9u) {
        uint32_t m = t / 3u, cc = t % 3u;
        ws[OFF_B0 + t] = (m == 0u) ? f1b0[cc] : (m == 1u) ? f2b0[cc] : (tab0[cc] + tbb0[cc]);
        return;
    }
    t -= 9u;
    if (t < 12u) {
        uint32_t i = t / 3u, m = t % 3u;
        float v;
        if (m == 0u)      v = f1w1[i] * mask[3081u + i];
        else if (m == 1u) v = f2w1[i] * mask[3081u + i];
        else              v = taw1[i] + tbw1[i];
        ws[OFF_W1 + t] = v;
        return;
    }
    t -= 12u;
    if (t < 3u) {
        ws[OFF_B1 + t] = (t == 0u) ? f1b1[0] : (t == 1u) ? f2b1[0] : (tab1[0] + tbb1[0]);
        return;
    }
    t -= 3u;
    if (t < 756u) {
        uint32_t m = t / 252u, j = t % 252u;
        ws[OFF_B2 + t] = (m == 0u) ? f1b2[j] : (m == 1u) ? f2b2[j] : (tab2[j] + tbb2[j]);
        return;
    }
}

// ---------------- prepass ----------------
__global__ __launch_bounds__(256) void prepass(const float* __restrict__ x,
                                               const float* __restrict__ w0xt,
                                               float* __restrict__ xpart)
{
    size_t r = (size_t)blockIdx.x * 256u + threadIdx.x;
    const float4* xr = (const float4*)(x + r * 1024u);
    float acc[9] = {0, 0, 0, 0, 0, 0, 0, 0, 0};
    for (int q = 0; q < 256; q++) {
        float4 xv = xr[q];
        #pragma unroll
        for (int c = 0; c < 9; c++) {
            float4 wv = ((const float4*)(w0xt + c * 1024))[q];
            acc[c] += xv.x * wv.x + xv.y * wv.y + xv.z * wv.z + xv.w * wv.w;
        }
    }
    #pragma unroll
    for (int c = 0; c < 9; c++) xpart[r * 9u + c] = acc[c];
}

// ---------------- packed half2 dot ----------------
__device__ inline float dot2u(uint32_t w, uint32_t h, float acc) {
#if __has_builtin(__builtin_amdgcn_fdot2)
    typedef _Float16 h2v __attribute__((ext_vector_type(2)));
    union { uint32_t u; h2v v; } a, b;
    a.u = w; b.u = h;
    return __builtin_amdgcn_fdot2(a.v, b.v, acc, false);
#else
    union { uint32_t u; _Float16 s[2]; } a, b;
    a.u = w; b.u = h;
    return acc + (float)a.s[0] * (float)b.s[0] + (float)a.s[1] * (float)b.s[1];
#endif
}

__device__ inline float fsig(float x) { return 1.0f / (1.0f + __expf(-x)); }
__device__ inline float ftanh(float x) { float e = __expf(2.0f * x); return 1.0f - 2.0f / (e + 1.0f); }

// ---------------- sequential CfC scan: in-wave K-reduction, ONE barrier/step ----------------
// 512 threads = 8 waves, 2/SIMD (256-VGPR budget). Wave w owns columns w*32..w*32+31;
// lanes l and l+32 are the two K-halves of column w*32+(l&31). 48 uint4 = 192 pinned
// weight regs/lane. Cross-half reduction = one __shfl_xor(a,32) per accumulator —
// no LDS exchange, no extra barrier. All lanes run layer-0/1 redundantly.
__global__ __launch_bounds__(512, 1) void seq_kernel(
    const float* __restrict__ xpart, const uint32_t* __restrict__ wh2,
    const float* __restrict__ b2g, const float* __restrict__ wh1g,
    const float* __restrict__ w0h_g, const float* __restrict__ b0_g,
    const float* __restrict__ w1_g, const float* __restrict__ b1_g,
    float* __restrict__ hx, float* __restrict__ h2f)
{
    __shared__ alignas(16) _Float16 hbuf[2][256];
    const int tid = threadIdx.x;
    const int w = tid >> 6;
    const int l = tid & 63;
    const int kh = l >> 5;
    const int col = w * 32 + (l & 31);
    const int b = blockIdx.x;
    const bool wrlane = (kh == 0) && (col < 252);

    if (tid < 256) { hbuf[0][tid] = (_Float16)0.0f; hbuf[1][tid] = (_Float16)0.0f; }

    // uniform layer-0/1 params (SGPR-resident)
    float w0h[27], b0[9], w1[12], b1[3];
    #pragma unroll
    for (int i = 0; i < 27; i++) w0h[i] = w0h_g[i];
    #pragma unroll
    for (int i = 0; i < 9; i++) b0[i] = b0_g[i];
    #pragma unroll
    for (int i = 0; i < 12; i++) w1[i] = w1_g[i];
    #pragma unroll
    for (int i = 0; i < 3; i++) b1[i] = b1_g[i];
    const int jc = (col < 252) ? col : 0;
    const float bj0 = b2g[jc], bj1 = b2g[252 + jc], bj2 = b2g[504 + jc];
    const float wh1a = wh1g[col], wh1b = wh1g[256 + col], wh1c = wh1g[512 + col];

    // ---- load this lane's 48 uint4 weights (coalesced), then PIN ----
    uint4 W[48];   // W[m*16+q]: matrix m, k-pairs kh*64+q*4..+3, column col
    const uint4* wq = (const uint4*)wh2;
    #pragma unroll
    for (int m = 0; m < 3; m++)
        #pragma unroll
        for (int q = 0; q < 16; q++)
            W[m * 16 + q] = wq[(((m * 16 + q) * 8 + w) << 6) + l];
    #pragma unroll
    for (int i = 0; i < 48; i++)
        asm volatile("" : "+v"(W[i].x), "+v"(W[i].y), "+v"(W[i].z), "+v"(W[i].w));

    float h0a = 0, h0b = 0, h0c = 0, h1 = 0, h2r = 0;
    const float* xp = xpart + (size_t)b * 9216u;
    float xpc[9];
    #pragma unroll
    for (int c = 0; c < 9; c++) xpc[c] = xp[c];
    __syncthreads();

    for (int t = 0; t < 1024; t++) {
        // ---- layer 0 + 1 (all lanes redundantly; registers only) ----
        float v[9];
        #pragma unroll
        for (int c = 0; c < 9; c++)
            v[c] = xpc[c] + b0[c] + h0a * w0h[c] + h0b * w0h[9 + c] + h0c * w0h[18 + c];
        if (t < 1023) {
            #pragma unroll
            for (int c = 0; c < 9; c++) xpc[c] = xp[(t + 1) * 9 + c];
        }
        float f10 = ftanh(v[0]), f11 = ftanh(v[1]), f12 = ftanh(v[2]);
        float f20 = ftanh(v[3]), f21 = ftanh(v[4]), f22 = ftanh(v[5]);
        float s0 = fsig(v[6]), s1 = fsig(v[7]), s2 = fsig(v[8]);
        float n0 = f10 * (1.0f - s0) + s0 * f20;
        float n1 = f11 * (1.0f - s1) + s1 * f21;
        float n2 = f12 * (1.0f - s2) + s2 * f22;
        float u0 = b1[0] + n0 * w1[0] + n1 * w1[3] + n2 * w1[6] + h1 * w1[9];
        float u1 = b1[1] + n0 * w1[1] + n1 * w1[4] + n2 * w1[7] + h1 * w1[10];
        float u2 = b1[2] + n0 * w1[2] + n1 * w1[5] + n2 * w1[8] + h1 * w1[11];
        float g1 = ftanh(u0), g2 = ftanh(u1), gs = fsig(u2);
        float h1n = g1 * (1.0f - gs) + gs * g2;
        h0a = n0; h0b = n1; h0c = n2; h1 = h1n;

        // ---- dots: K-half kh, 16 broadcast uint4 h-reads ----
        const uint4* xq = (const uint4*)hbuf[t & 1];
        uint4 hq[16];
        #pragma unroll
        for (int q = 0; q < 16; q++) hq[q] = xq[kh * 16 + q];
        float am0[2] = { 0, 0 }, am1[2] = { 0, 0 }, am2[2] = { 0, 0 };
        #pragma unroll
        for (int q = 0; q < 16; q++) {
            uint4 h4 = hq[q];
            const int s = q & 1;
            uint4 w0v = W[q];
            am0[s] = dot2u(w0v.x, h4.x, am0[s]);
            am0[s] = dot2u(w0v.y, h4.y, am0[s]);
            am0[s] = dot2u(w0v.z, h4.z, am0[s]);
            am0[s] = dot2u(w0v.w, h4.w, am0[s]);
            uint4 w1v = W[16 + q];
            am1[s] = dot2u(w1v.x, h4.x, am1[s]);
            am1[s] = dot2u(w1v.y, h4.y, am1[s]);
            am1[s] = dot2u(w1v.z, h4.z, am1[s]);
            am1[s] = dot2u(w1v.w, h4.w, am1[s]);
            uint4 w2v = W[32 + q];
            am2[s] = dot2u(w2v.x, h4.x, am2[s]);
            am2[s] = dot2u(w2v.y, h4.y, am2[s]);
            am2[s] = dot2u(w2v.z, h4.z, am2[s]);
            am2[s] = dot2u(w2v.w, h4.w, am2[s]);
        }
        float a0 = am0[0] + am0[1];
        float a1 = am1[0] + am1[1];
        float a2 = am2[0] + am2[1];
        // ---- in-wave K-half reduction (lane l <-> l+32) ----
        a0 += __shfl_xor(a0, 32);
        a1 += __shfl_xor(a1, 32);
        a2 += __shfl_xor(a2, 32);
        // ---- epilogue (all lanes; only kh==0 writes) ----
        a0 += h1n * wh1a;
        a1 += h1n * wh1b;
        a2 += h1n * wh1c;
        float ff1 = ftanh(a0 + bj0), ff2 = ftanh(a1 + bj1), tg = fsig(a2 + bj2);
        float h2n = ff1 * (1.0f - tg) + tg * ff2;
        if (wrlane) { hbuf[(t & 1) ^ 1][col] = (_Float16)h2n; h2r = h2n; }
        __syncthreads();   // ONE barrier: hbuf[next] visible; prior reads complete
    }
    if (wrlane) { h2f[b * 252 + col] = h2r; hx[b * 256 + 4 + col] = h2r; }
    if (tid == 0) { hx[b * 256 + 0] = h0a; hx[b * 256 + 1] = h0b; hx[b * 256 + 2] = h0c; hx[b * 256 + 3] = h1; }
}

// ---------------- output projections ----------------
__global__ __launch_bounds__(256) void proj1(const float* __restrict__ h2f,
                                             const float* __restrict__ hw,
                                             const float* __restrict__ hb,
                                             float* __restrict__ hid)
{
    int c = blockIdx.x * 256 + threadIdx.x;
    int b = blockIdx.y;
    float acc = hb[c];
    const float* h2 = h2f + b * 252;
    #pragma unroll 4
    for (int k = 0; k < 252; k++) acc += h2[k] * hw[k * 1024 + c];
    hid[b * 1024 + c] = acc;
}

__global__ __launch_bounds__(256) void proj2(const float* __restrict__ hid,
                                             const float* __restrict__ ow,
                                             const float* __restrict__ ob,
                                             float* __restrict__ outp)
{
    int c = blockIdx.x * 256 + threadIdx.x;
    int b = blockIdx.y;
    float acc = ob[c];
    const float* hr = hid + b * 1024;
    #pragma unroll 4
    for (int k = 0; k < 1024; k++) acc += hr[k] * ow[k * 1024 + c];
    outp[b * 1024 + c] = acc;
}

// ---------------- host launcher ----------------
extern "C" void kernel_launch(void* const* d_in, const int* in_sizes, int n_in,
                              void* d_out, int out_size, void* d_ws, size_t ws_size,
                              hipStream_t stream) {
    const float* x = (const float*)d_in[0];
    const float* l0_ff1_w = (const float*)d_in[1];
    const float* l0_ff1_b = (const float*)d_in[2];
    const float* l0_ff2_w = (const float*)d_in[3];
    const float* l0_ff2_b = (const float*)d_in[4];
    const float* l0_ta_w  = (const float*)d_in[5];
    const float* l0_ta_b  = (const float*)d_in[6];
    const float* l0_tb_w  = (const float*)d_in[7];
    const float* l0_tb_b  = (const float*)d_in[8];
    const float* l1_ff1_w = (const float*)d_in[9];
    const float* l1_ff1_b = (const float*)d_in[10];
    const float* l1_ff2_w = (const float*)d_in[11];
    const float* l1_ff2_b = (const float*)d_in[12];
    const float* l1_ta_w  = (const float*)d_in[13];
    const float* l1_ta_b  = (const float*)d_in[14];
    const float* l1_tb_w  = (const float*)d_in[15];
    const float* l1_tb_b  = (const float*)d_in[16];
    const float* l2_ff1_w = (const float*)d_in[17];
    const float* l2_ff1_b = (const float*)d_in[18];
    const float* l2_ff2_w = (const float*)d_in[19];
    const float* l2_ff2_b = (const float*)d_in[20];
    const float* l2_ta_w  = (const float*)d_in[21];
    const float* l2_ta_b  = (const float*)d_in[22];
    const float* l2_tb_w  = (const float*)d_in[23];
    const float* l2_tb_b  = (const float*)d_in[24];
    const float* hproj_w  = (const float*)d_in[25];
    const float* hproj_b  = (const float*)d_in[26];
    const float* oproj_w  = (const float*)d_in[27];
    const float* oproj_b  = (const float*)d_in[28];
    (void)in_sizes; (void)n_in; (void)out_size; (void)ws_size;

    float* ws = (float*)d_ws;
    uint32_t* wsu = (uint32_t*)d_ws;
    float* out = (float*)d_out;

    hipLaunchKernelGGL(gen_masks, dim3(1), dim3(256), 0, stream, ws + OFF_MASK);
    hipLaunchKernelGGL(prep_weights, dim3(427), dim3(256), 0, stream,
                       l0_ff1_w, l0_ff2_w, l0_ta_w, l0_tb_w,
                       l0_ff1_b, l0_ff2_b, l0_ta_b, l0_tb_b,
                       l1_ff1_w, l1_ff2_w, l1_ta_w, l1_tb_w,
                       l1_ff1_b, l1_ff2_b, l1_ta_b, l1_tb_b,
                       l2_ff1_w, l2_ff2_w, l2_ta_w, l2_tb_w,
                       l2_ff1_b, l2_ff2_b, l2_ta_b, l2_tb_b,
                       ws);
    hipLaunchKernelGGL(prepass, dim3(256), dim3(256), 0, stream,
                       x, ws + OFF_W0XT, ws + OFF_XPART);
    hipLaunchKernelGGL(seq_kernel, dim3(64), dim3(512), 0, stream,
                       ws + OFF_XPART, wsu + OFF_WH2, ws + OFF_B2, ws + OFF_WH1,
                       ws + OFF_W0H, ws + OFF_B0, ws + OFF_W1, ws + OFF_B1,
                       out + 65536, ws + OFF_H2F);
    hipLaunchKernelGGL(proj1, dim3(4, 64), dim3(256), 0, stream,
                       ws + OFF_H2F, hproj_w, hproj_b, ws + OFF_HID);
    hipLaunchKernelGGL(proj2, dim3(4, 64), dim3(256), 0, stream,
                       ws + OFF_HID, oproj_w, oproj_b, out);
}

// Round 22
// 2005.925 us; speedup vs baseline: 1.3075x; 1.3075x over previous
//
#include <hip/hip_runtime.h>
#include <stdint.h>

// ---------------- workspace layout (4-byte element offsets) ----------------
static constexpr uint32_t OFF_MASK  = 0;        // 66841 floats (dead after prep_weights)
static constexpr uint32_t OFF_HID   = 0;        // 65536 floats (aliases MASK; used by proj1/2)
static constexpr uint32_t OFF_W0XT  = 66844;    // [9][1024]
static constexpr uint32_t OFF_W0H   = 76060;    // [3][9]
static constexpr uint32_t OFF_B0    = 76088;    // [9]
static constexpr uint32_t OFF_W1    = 76100;    // [4][3]
static constexpr uint32_t OFF_B1    = 76112;    // [3]
static constexpr uint32_t OFF_WH2   = 76116;    // 98304 u32 half2; uint4 layout [m][kq][q][g][l]
static constexpr uint32_t OFF_WH1   = 174420;   // [3][256] fp32 h1-weights per column (zero-padded)
static constexpr uint32_t OFF_B2    = 175188;   // [3][252]
static constexpr uint32_t OFF_XPART = 175948;   // [64][1024][9]
static constexpr uint32_t OFF_H2F   = 765772;   // [64][252]

// ---------------- 128-bit helpers ----------------
struct U128 { uint64_t lo, hi; };
__device__ inline U128 mul128(U128 a, U128 b) {
    U128 r; r.lo = a.lo * b.lo;
    r.hi = a.hi * b.lo + a.lo * b.hi + __umul64hi(a.lo, b.lo);
    return r;
}
__device__ inline U128 add128(U128 a, U128 b) {
    U128 r; r.lo = a.lo + b.lo; r.hi = a.hi + b.hi + (r.lo < b.lo); return r;
}
__device__ inline U128 pcg_mult() { U128 m; m.lo = 0x4385df649fccf645ull; m.hi = 0x2360ed051fc65da4ull; return m; }
__device__ inline void pcg_step(U128& st, U128 inc) { st = add128(mul128(st, pcg_mult()), inc); }

// ---------------- numpy PCG64(SeedSequence(0)) — confirmed (round 13) ----------------
__device__ void pcg_init_np(U128& st, U128& inc) {
    const uint32_t IA = 0x43b0d7e5u, MA = 0x931e8875u, IB = 0x8b51f9ddu, MB = 0x58f38dedu;
    const uint32_t ML = 0xca01f9ddu, MR = 0x4973f715u;
    uint32_t hc = IA;
    auto hmix = [&](uint32_t val) -> uint32_t {
        val ^= hc; hc *= MA; val *= hc; val ^= val >> 16; return val;
    };
    auto mixf = [&](uint32_t x, uint32_t y) -> uint32_t {
        uint32_t r = (x * ML) - (y * MR); r ^= r >> 16; return r;   // SUB mix (round-13 fix)
    };
    uint32_t pool[4];
    for (int i = 0; i < 4; i++) pool[i] = hmix(0u);
    for (int s = 0; s < 4; s++)
        for (int d = 0; d < 4; d++)
            if (s != d) pool[d] = mixf(pool[d], hmix(pool[s]));
    uint32_t hb = IB;
    uint32_t s32[8];
    for (int i = 0; i < 8; i++) {
        uint32_t dv = pool[i & 3];
        dv ^= hb; hb *= MB; dv *= hb; dv ^= dv >> 16;
        s32[i] = dv;
    }
    uint64_t w[4];
    for (int k = 0; k < 4; k++)
        w[k] = (uint64_t)s32[2 * k] | ((uint64_t)s32[2 * k + 1] << 32);
    U128 initstate; initstate.hi = w[0]; initstate.lo = w[1];
    inc.lo = (w[3] << 1) | 1ull;
    inc.hi = (w[2] << 1) | (w[3] >> 63);
    st.lo = 0; st.hi = 0;
    pcg_step(st, inc);
    st = add128(st, initstate);
    pcg_step(st, inc);
}
__device__ inline uint64_t pcg_draw(U128& st, U128 inc) {
    pcg_step(st, inc);
    uint64_t x = st.hi ^ st.lo;
    uint32_t rot = (uint32_t)(st.hi >> 58);
    return (x >> rot) | (x << ((64u - rot) & 63u));
}
__device__ void pcg_advance(U128& st, U128 inc, uint64_t delta) {
    U128 am; am.lo = 1; am.hi = 0;
    U128 ap; ap.lo = 0; ap.hi = 0;
    U128 cm = pcg_mult(), cp = inc;
    while (delta) {
        if (delta & 1) { am = mul128(am, cm); ap = add128(mul128(ap, cm), cp); }
        U128 cm1 = cm; cm1.lo += 1; cm1.hi += (cm1.lo == 0);
        cp = mul128(cm1, cp);
        cm = mul128(cm, cm);
        delta >>= 1;
    }
    st = add128(mul128(st, am), ap);
}

// ---------------- mask generation (parallel: 33 blocks x 256 thr x 8 draws) ----------------
__global__ __launch_bounds__(256) void gen_masks(float* __restrict__ mask) {
    const uint32_t gtid = blockIdx.x * 256u + threadIdx.x;
    U128 s, inc; pcg_init_np(s, inc);
    pcg_advance(s, inc, (uint64_t)gtid * 8u);
    uint32_t base = gtid * 8u;
    #pragma unroll
    for (uint32_t q = 0; q < 8u; q++) {
        uint64_t o = pcg_draw(s, inc);
        uint32_t idx = base + q;
        if (idx < 66841u) mask[idx] = (o >> 63) ? 0.0f : 1.0f;
    }
}

// ---------------- weight preprocessing ----------------
// WH2 uint4 layout [m][kq][q][g][l]: lin = (((m*4+kq)*8+q)*4+g)*64+l; component c
// holds half2 pair p = kq*32+q*4+c -> l2 rows (1+2p, 2+2p), column jp = g*64+l.
__global__ __launch_bounds__(256) void prep_weights(
    const float* f1w0, const float* f2w0, const float* taw0, const float* tbw0,
    const float* f1b0, const float* f2b0, const float* tab0, const float* tbb0,
    const float* f1w1, const float* f2w1, const float* taw1, const float* tbw1,
    const float* f1b1, const float* f2b1, const float* tab1, const float* tbb1,
    const float* f1w2, const float* f2w2, const float* taw2, const float* tbw2,
    const float* f1b2, const float* f2b2, const float* tab2, const float* tbb2,
    float* ws)
{
    const float* mask = ws + OFF_MASK;
    uint32_t id = blockIdx.x * 256u + threadIdx.x;
    if (id < 98304u) {
        uint32_t lin = id >> 2, c = id & 3u;
        uint32_t m = lin / 8192u, rem = lin % 8192u;
        uint32_t kq = rem / 2048u, rem2 = rem % 2048u;
        uint32_t q = rem2 / 256u, rem3 = rem2 % 256u;
        uint32_t g = rem3 / 64u, l = rem3 % 64u;
        uint32_t p = kq * 32u + q * 4u + c;
        uint32_t jp = g * 64u + l;
        auto wv = [&](uint32_t k) -> float {
            if (m == 0u) return f1w2[k * 252u + jp] * mask[3085u + k * 252u + jp];
            if (m == 1u) return f2w2[k * 252u + jp] * mask[3085u + k * 252u + jp];
            return taw2[k * 252u + jp] + tbw2[k * 252u + jp];
        };
        float a = 0.0f, bb = 0.0f;
        if (jp < 252u && p < 126u) { a = wv(1u + 2u * p); bb = wv(2u + 2u * p); }
        union { uint32_t u; _Float16 h[2]; } pk;
        pk.h[0] = (_Float16)a; pk.h[1] = (_Float16)bb;
        ((uint32_t*)ws)[OFF_WH2 + lin * 4u + c] = pk.u;
        return;
    }
    uint32_t t = id - 98304u;
    if (t < 768u) {  // WH1 fp32 (l2 row 0 = h1 weight), zero-padded to 256
        uint32_t mm = t / 256u, jp = t % 256u;
        float v = 0.0f;
        if (jp < 252u) {
            if (mm == 0u)      v = f1w2[jp] * mask[3085u + jp];
            else if (mm == 1u) v = f2w2[jp] * mask[3085u + jp];
            else               v = taw2[jp] + tbw2[jp];
        }
        ws[OFF_WH1 + t] = v;
        return;
    }
    t -= 768u;
    if (t < 9216u) {  // W0xT [c][k]
        uint32_t c = t / 1024u, k = t % 1024u, m = c / 3u, cc = c % 3u;
        float v;
        if (m == 0u)      v = f1w0[k * 3u + cc] * mask[k * 3u + cc];
        else if (m == 1u) v = f2w0[k * 3u + cc] * mask[k * 3u + cc];
        else              v = taw0[k * 3u + cc] + tbw0[k * 3u + cc];
        ws[OFF_W0XT + c * 1024u + k] = v;
        return;
    }
    t -= 9216u;
    if (t < 27u) {  // W0h [i][c]
        uint32_t i = t / 9u, c = t % 9u, m = c / 3u, cc = c % 3u, k = 1024u + i;
        float v;
        if (m == 0u)      v = f1w0[k * 3u + cc] * mask[k * 3u + cc];
        else if (m == 1u) v = f2w0[k * 3u + cc] * mask[k * 3u + cc];
        else              v = taw0[k * 3u + cc] + tbw0[k * 3u + cc];
        ws[OFF_W0H + t] = v;
        return;
    }
    t -= 27u;
    if (t < 9u) {
        uint32_t m = t / 3u, cc = t % 3u;
        ws[OFF_B0 + t] = (m == 0u) ? f1b0[cc] : (m == 1u) ? f2b0[cc] : (tab0[cc] + tbb0[cc]);
        return;
    }
    t -= 9u;
    if (t < 12u) {
        uint32_t i = t / 3u, m = t % 3u;
        float v;
        if (m == 0u)      v = f1w1[i] * mask[3081u + i];
        else if (m == 1u) v = f2w1[i] * mask[3081u + i];
        else              v = taw1[i] + tbw1[i];
        ws[OFF_W1 + t] = v;
        return;
    }
    t -= 12u;
    if (t < 3u) {
        ws[OFF_B1 + t] = (t == 0u) ? f1b1[0] : (t == 1u) ? f2b1[0] : (tab1[0] + tbb1[0]);
        return;
    }
    t -= 3u;
    if (t < 756u) {
        uint32_t m = t / 252u, j = t % 252u;
        ws[OFF_B2 + t] = (m == 0u) ? f1b2[j] : (m == 1u) ? f2b2[j] : (tab2[j] + tbb2[j]);
        return;
    }
}

// ---------------- prepass ----------------
__global__ __launch_bounds__(256) void prepass(const float* __restrict__ x,
                                               const float* __restrict__ w0xt,
                                               float* __restrict__ xpart)
{
    size_t r = (size_t)blockIdx.x * 256u + threadIdx.x;
    const float4* xr = (const float4*)(x + r * 1024u);
    float acc[9] = {0, 0, 0, 0, 0, 0, 0, 0, 0};
    for (int q = 0; q < 256; q++) {
        float4 xv = xr[q];
        #pragma unroll
        for (int c = 0; c < 9; c++) {
            float4 wv = ((const float4*)(w0xt + c * 1024))[q];
            acc[c] += xv.x * wv.x + xv.y * wv.y + xv.z * wv.z + xv.w * wv.w;
        }
    }
    #pragma unroll
    for (int c = 0; c < 9; c++) xpart[r * 9u + c] = acc[c];
}

// ---------------- packed half2 dot ----------------
__device__ inline float dot2u(uint32_t w, uint32_t h, float acc) {
#if __has_builtin(__builtin_amdgcn_fdot2)
    typedef _Float16 h2v __attribute__((ext_vector_type(2)));
    union { uint32_t u; h2v v; } a, b;
    a.u = w; b.u = h;
    return __builtin_amdgcn_fdot2(a.v, b.v, acc, false);
#else
    union { uint32_t u; _Float16 s[2]; } a, b;
    a.u = w; b.u = h;
    return acc + (float)a.s[0] * (float)b.s[0] + (float)a.s[1] * (float)b.s[1];
#endif
}

__device__ inline float fsig(float x) { return 1.0f / (1.0f + __expf(-x)); }
__device__ inline float ftanh(float x) { float e = __expf(2.0f * x); return 1.0f - 2.0f / (e + 1.0f); }

// ---------------- sequential CfC scan: (m,kq)-wave split, 4 cols/lane (R20 best) ----------------
__global__ __launch_bounds__(768, 1) void seq_kernel(
    const float* __restrict__ xpart, const uint32_t* __restrict__ wh2,
    const float* __restrict__ b2g, const float* __restrict__ wh1g,
    const float* __restrict__ w0h_g, const float* __restrict__ b0_g,
    const float* __restrict__ w1_g, const float* __restrict__ b1_g,
    float* __restrict__ hx, float* __restrict__ h2f)
{
    __shared__ alignas(16) _Float16 hbuf[2][256];
    __shared__ float part[12][256];
    const int tid = threadIdx.x;
    const int w = tid >> 6;
    const int m = w >> 2;
    const int kq = w & 3;
    const int l = tid & 63;
    const int b = blockIdx.x;
    const bool red = (m == 0);              // reduction + layer-0/1 group (tid<256)

    if (tid < 256) { hbuf[0][tid] = (_Float16)0.0f; hbuf[1][tid] = (_Float16)0.0f; }

    float w0h[27], b0[9], w1[12], b1[3];
    #pragma unroll
    for (int i = 0; i < 27; i++) w0h[i] = w0h_g[i];
    #pragma unroll
    for (int i = 0; i < 9; i++) b0[i] = b0_g[i];
    #pragma unroll
    for (int i = 0; i < 12; i++) w1[i] = w1_g[i];
    #pragma unroll
    for (int i = 0; i < 3; i++) b1[i] = b1_g[i];
    const int j = (tid < 256) ? tid : 0;    // reduction column
    const int jc = (j < 252) ? j : 0;
    const float bj0 = b2g[jc], bj1 = b2g[252 + jc], bj2 = b2g[504 + jc];
    const float wh1a = wh1g[j], wh1b = wh1g[256 + j], wh1c = wh1g[512 + j];

    // ---- load this lane's 32 uint4 weights (coalesced), then PIN ----
    uint4 W[32];   // W[g*8+q]: col g*64+l, k-pairs kq*32+q*4..+3 of matrix m
    const uint4* wq = (const uint4*)wh2;
    #pragma unroll
    for (int q = 0; q < 8; q++)
        #pragma unroll
        for (int g = 0; g < 4; g++)
            W[g * 8 + q] = wq[((((m * 4 + kq) * 8 + q) * 4 + g) << 6) + l];
    #pragma unroll
    for (int i = 0; i < 32; i++)
        asm volatile("" : "+v"(W[i].x), "+v"(W[i].y), "+v"(W[i].z), "+v"(W[i].w));

    float h0a = 0, h0b = 0, h0c = 0, h1 = 0, h2r = 0;
    const float* xp = xpart + (size_t)b * 9216u;
    float xpc[9];
    if (red) {
        #pragma unroll
        for (int c = 0; c < 9; c++) xpc[c] = xp[c];
    }
    __syncthreads();

    for (int t = 0; t < 1024; t++) {
        float h1n = 0.0f;
        if (red) {
            float v[9];
            #pragma unroll
            for (int c = 0; c < 9; c++)
                v[c] = xpc[c] + b0[c] + h0a * w0h[c] + h0b * w0h[9 + c] + h0c * w0h[18 + c];
            if (t < 1023) {
                #pragma unroll
                for (int c = 0; c < 9; c++) xpc[c] = xp[(t + 1) * 9 + c];
            }
            float f10 = ftanh(v[0]), f11 = ftanh(v[1]), f12 = ftanh(v[2]);
            float f20 = ftanh(v[3]), f21 = ftanh(v[4]), f22 = ftanh(v[5]);
            float s0 = fsig(v[6]), s1 = fsig(v[7]), s2 = fsig(v[8]);
            float n0 = f10 * (1.0f - s0) + s0 * f20;
            float n1 = f11 * (1.0f - s1) + s1 * f21;
            float n2 = f12 * (1.0f - s2) + s2 * f22;
            float u0 = b1[0] + n0 * w1[0] + n1 * w1[3] + n2 * w1[6] + h1 * w1[9];
            float u1 = b1[1] + n0 * w1[1] + n1 * w1[4] + n2 * w1[7] + h1 * w1[10];
            float u2 = b1[2] + n0 * w1[2] + n1 * w1[5] + n2 * w1[8] + h1 * w1[11];
            float g1 = ftanh(u0), g2 = ftanh(u1), gs = fsig(u2);
            h1n = g1 * (1.0f - gs) + gs * g2;
            h0a = n0; h0b = n1; h0c = n2; h1 = h1n;
        }
        const uint4* xq = (const uint4*)hbuf[t & 1];
        uint4 hq[8];
        #pragma unroll
        for (int q = 0; q < 8; q++) hq[q] = xq[kq * 8 + q];
        float accA[4] = { 0, 0, 0, 0 }, accB[4] = { 0, 0, 0, 0 };
        #pragma unroll
        for (int q = 0; q < 8; q++) {
            uint4 h4 = hq[q];
            #pragma unroll
            for (int g = 0; g < 4; g++) {
                uint4 w4 = W[g * 8 + q];
                accA[g] = dot2u(w4.x, h4.x, accA[g]);
                accB[g] = dot2u(w4.y, h4.y, accB[g]);
                accA[g] = dot2u(w4.z, h4.z, accA[g]);
                accB[g] = dot2u(w4.w, h4.w, accB[g]);
            }
        }
        const int row = m * 4 + kq;
        #pragma unroll
        for (int g = 0; g < 4; g++)
            part[row][g * 64 + l] = accA[g] + accB[g];
        __syncthreads();   // barrier 1: partials visible; all hbuf reads done
        if (red) {
            float a0 = (part[0][j] + part[1][j]) + (part[2][j] + part[3][j]) + h1n * wh1a;
            float a1 = (part[4][j] + part[5][j]) + (part[6][j] + part[7][j]) + h1n * wh1b;
            float a2 = (part[8][j] + part[9][j]) + (part[10][j] + part[11][j]) + h1n * wh1c;
            float ff1 = ftanh(a0 + bj0), ff2 = ftanh(a1 + bj1), tg = fsig(a2 + bj2);
            float h2n = ff1 * (1.0f - tg) + tg * ff2;
            if (j < 252) { hbuf[(t & 1) ^ 1][j] = (_Float16)h2n; h2r = h2n; }
        }
        __syncthreads();   // barrier 2: hbuf[next] visible
    }
    if (red && j < 252) { h2f[b * 252 + j] = h2r; hx[b * 256 + 4 + j] = h2r; }
    if (tid == 0) { hx[b * 256 + 0] = h0a; hx[b * 256 + 1] = h0b; hx[b * 256 + 2] = h0c; hx[b * 256 + 3] = h1; }
}

// ---------------- output projections ----------------
__global__ __launch_bounds__(256) void proj1(const float* __restrict__ h2f,
                                             const float* __restrict__ hw,
                                             const float* __restrict__ hb,
                                             float* __restrict__ hid)
{
    int c = blockIdx.x * 256 + threadIdx.x;
    int b = blockIdx.y;
    float acc = hb[c];
    const float* h2 = h2f + b * 252;
    #pragma unroll 4
    for (int k = 0; k < 252; k++) acc += h2[k] * hw[k * 1024 + c];
    hid[b * 1024 + c] = acc;
}

__global__ __launch_bounds__(256) void proj2(const float* __restrict__ hid,
                                             const float* __restrict__ ow,
                                             const float* __restrict__ ob,
                                             float* __restrict__ outp)
{
    int c = blockIdx.x * 256 + threadIdx.x;
    int b = blockIdx.y;
    float acc = ob[c];
    const float* hr = hid + b * 1024;
    #pragma unroll 4
    for (int k = 0; k < 1024; k++) acc += hr[k] * ow[k * 1024 + c];
    outp[b * 1024 + c] = acc;
}

// ---------------- host launcher ----------------
extern "C" void kernel_launch(void* const* d_in, const int* in_sizes, int n_in,
                              void* d_out, int out_size, void* d_ws, size_t ws_size,
                              hipStream_t stream) {
    const float* x = (const float*)d_in[0];
    const float* l0_ff1_w = (const float*)d_in[1];
    const float* l0_ff1_b = (const float*)d_in[2];
    const float* l0_ff2_w = (const float*)d_in[3];
    const float* l0_ff2_b = (const float*)d_in[4];
    const float* l0_ta_w  = (const float*)d_in[5];
    const float* l0_ta_b  = (const float*)d_in[6];
    const float* l0_tb_w  = (const float*)d_in[7];
    const float* l0_tb_b  = (const float*)d_in[8];
    const float* l1_ff1_w = (const float*)d_in[9];
    const float* l1_ff1_b = (const float*)d_in[10];
    const float* l1_ff2_w = (const float*)d_in[11];
    const float* l1_ff2_b = (const float*)d_in[12];
    const float* l1_ta_w  = (const float*)d_in[13];
    const float* l1_ta_b  = (const float*)d_in[14];
    const float* l1_tb_w  = (const float*)d_in[15];
    const float* l1_tb_b  = (const float*)d_in[16];
    const float* l2_ff1_w = (const float*)d_in[17];
    const float* l2_ff1_b = (const float*)d_in[18];
    const float* l2_ff2_w = (const float*)d_in[19];
    const float* l2_ff2_b = (const float*)d_in[20];
    const float* l2_ta_w  = (const float*)d_in[21];
    const float* l2_ta_b  = (const float*)d_in[22];
    const float* l2_tb_w  = (const float*)d_in[23];
    const float* l2_tb_b  = (const float*)d_in[24];
    const float* hproj_w  = (const float*)d_in[25];
    const float* hproj_b  = (const float*)d_in[26];
    const float* oproj_w  = (const float*)d_in[27];
    const float* oproj_b  = (const float*)d_in[28];
    (void)in_sizes; (void)n_in; (void)out_size; (void)ws_size;

    float* ws = (float*)d_ws;
    uint32_t* wsu = (uint32_t*)d_ws;
    float* out = (float*)d_out;

    hipLaunchKernelGGL(gen_masks, dim3(33), dim3(256), 0, stream, ws + OFF_MASK);
    hipLaunchKernelGGL(prep_weights, dim3(427), dim3(256), 0, stream,
                       l0_ff1_w, l0_ff2_w, l0_ta_w, l0_tb_w,
                       l0_ff1_b, l0_ff2_b, l0_ta_b, l0_tb_b,
                       l1_ff1_w, l1_ff2_w, l1_ta_w, l1_tb_w,
                       l1_ff1_b, l1_ff2_b, l1_ta_b, l1_tb_b,
                       l2_ff1_w, l2_ff2_w, l2_ta_w, l2_tb_w,
                       l2_ff1_b, l2_ff2_b, l2_ta_b, l2_tb_b,
                       ws);
    hipLaunchKernelGGL(prepass, dim3(256), dim3(256), 0, stream,
                       x, ws + OFF_W0XT, ws + OFF_XPART);
    hipLaunchKernelGGL(seq_kernel, dim3(64), dim3(768), 0, stream,
                       ws + OFF_XPART, wsu + OFF_WH2, ws + OFF_B2, ws + OFF_WH1,
                       ws + OFF_W0H, ws + OFF_B0, ws + OFF_W1, ws + OFF_B1,
                       out + 65536, ws + OFF_H2F);
    hipLaunchKernelGGL(proj1, dim3(4, 64), dim3(256), 0, stream,
                       ws + OFF_H2F, hproj_w, hproj_b, ws + OFF_HID);
    hipLaunchKernelGGL(proj2, dim3(4, 64), dim3(256), 0, stream,
                       ws + OFF_HID, oproj_w, oproj_b, out);
}